// Round 3
// baseline (317.063 us; speedup 1.0000x reference)
//
#include <hip/hip_runtime.h>

#define BATCH 16
#define CCH   256
#define WLEN  4096
#define OCH   256
#define KW    3
#define CK    768      // CCH*KW
#define CHUNK 32       // channels per K-chunk
#define NCHUNK 8       // CCH / CHUNK
#define SLD   104      // Sl row stride (shorts): 96 ck + 8 pad, keeps 16B align

typedef short bf16x8 __attribute__((ext_vector_type(8)));
typedef short bf16x4 __attribute__((ext_vector_type(4)));
typedef float f32x4  __attribute__((ext_vector_type(4)));

__device__ inline short f2bf(float f) {
    union { float f; unsigned u; } v; v.f = f;
    unsigned r = v.u + 0x7FFFu + ((v.u >> 16) & 1u);   // RNE
    return (short)(r >> 16);
}

// ---------------- kernel 1: weight fp32 [256][768] -> bf16 ----------------
__global__ void wconv_kernel(const float* __restrict__ w, short* __restrict__ wb) {
    int i = blockIdx.x * 256 + threadIdx.x;
    wb[i] = f2bf(w[i]);
}

// ---------------- fused kernel v4: no LDS window staging, direct global taps ----------------
// grid: 16 b x 64 wt = 1024 blocks, 512 thr (8 waves), 3 blocks/CU (LDS 26.6 KB).
// Gather reads x taps straight from global (12 KB/chunk working set -> L1/L2-hot,
// lanes ~consecutive -> coalesced). LDS holds only the gathered B-tile (double-buffered).
// Per iter: gather(c+1) loads->cvt->Sl[(c+1)&1]  ||  mfma(c) from Sl[c&1]; one barrier.
__global__ __launch_bounds__(512, 6)
void deform_fused_kernel(const float* __restrict__ x,
                         const short* __restrict__ wb,
                         const float* __restrict__ off,
                         const float* __restrict__ msk,
                         const float* __restrict__ bias,
                         float* __restrict__ out) {
    __shared__ short SlS[2][64 * SLD];       // 2 x 13312 B: gathered B-tile [w][96ck]

    const int t      = threadIdx.x;
    const int b      = blockIdx.x >> 6;
    const int wt     = blockIdx.x & 63;
    const int lane   = t & 63;
    const int wv     = t >> 6;
    const int lr     = lane & 15;
    const int lq     = lane >> 4;
    const int wg     = wt * 64 + lane;

    // ---- per-lane sampling params: clamped global byte offsets + masked weights ----
    int   gb0[3], gb1[3];
    float rw0[3], rw1[3];
#pragma unroll
    for (int k = 0; k < 3; ++k) {
        float o  = off[b * (KW * WLEN) + k * WLEN + wg];
        float m  = msk[b * (KW * WLEN) + k * WLEN + wg];
        float p  = (float)(wg - 1 + k) + o;
        float pf = floorf(p);
        float w1 = p - pf;
        int i0 = (int)pf;
        int i1 = i0 + 1;
        bool v0 = (i0 >= 0) & (i0 < WLEN);
        bool v1 = (i1 >= 0) & (i1 < WLEN);
        gb0[k] = min(max(i0, 0), WLEN - 1) * 4;   // in-bounds byte offset; weight 0 if invalid
        gb1[k] = min(max(i1, 0), WLEN - 1) * 4;
        rw0[k] = v0 ? m * (1.0f - w1) : 0.0f;
        rw1[k] = v1 ? m * w1 : 0.0f;
    }

    const float* xb = x + (size_t)b * CCH * WLEN;

    f32x4 acc[2][4];
#pragma unroll
    for (int i = 0; i < 2; ++i)
#pragma unroll
        for (int j = 0; j < 4; ++j)
            acc[i][j] = (f32x4){0.f, 0.f, 0.f, 0.f};

    // ---- gather chunk c: wave wv samples its 4 channels from GLOBAL -> SlS[sbuf] ----
    auto gather = [&](int c, int sbuf) {
        short obuf[12];
#pragma unroll
        for (int dc = 0; dc < 4; ++dc) {
            const char* xrow = (const char*)(xb + (size_t)(c * CHUNK + wv * 4 + dc) * WLEN);
#pragma unroll
            for (int k = 0; k < 3; ++k) {
                float v0 = *(const float*)(xrow + gb0[k]);
                float v1 = *(const float*)(xrow + gb1[k]);
                obuf[dc * 3 + k] = f2bf(rw0[k] * v0 + rw1[k] * v1);
            }
        }
        short* sp = &SlS[sbuf][lane * SLD + wv * 12];   // cols [wv*12, wv*12+12)
#pragma unroll
        for (int j = 0; j < 3; ++j)
            *reinterpret_cast<bf16x4*>(sp + j * 4) =
                *reinterpret_cast<const bf16x4*>(&obuf[j * 4]);
    };

    // ---- MFMA chunk c: A-frags from global (L2-hot wb), B-frags from SlS[sbuf] ----
    auto mfma_chunk = [&](int c, int sbuf) {
#pragma unroll
        for (int ks = 0; ks < 3; ++ks) {
            bf16x8 af[2], bfv[4];
#pragma unroll
            for (int mt = 0; mt < 2; ++mt)
                af[mt] = *reinterpret_cast<const bf16x8*>(
                    wb + (size_t)(wv * 32 + mt * 16 + lr) * CK + c * 96 + ks * 32 + lq * 8);
#pragma unroll
            for (int nt = 0; nt < 4; ++nt)
                bfv[nt] = *reinterpret_cast<const bf16x8*>(
                    &SlS[sbuf][(nt * 16 + lr) * SLD + ks * 32 + lq * 8]);
            __builtin_amdgcn_s_setprio(1);
#pragma unroll
            for (int mt = 0; mt < 2; ++mt)
#pragma unroll
                for (int nt = 0; nt < 4; ++nt)
                    acc[mt][nt] = __builtin_amdgcn_mfma_f32_16x16x32_bf16(
                        af[mt], bfv[nt], acc[mt][nt], 0, 0, 0);
            __builtin_amdgcn_s_setprio(0);
        }
    };

    // ---- pipeline: gather(c+1) overlaps mfma(c); one barrier per chunk ----
    gather(0, 0);
    __syncthreads();
#pragma unroll
    for (int c = 0; c < NCHUNK; ++c) {
        if (c < NCHUNK - 1) gather(c + 1, (c + 1) & 1);
        mfma_chunk(c, c & 1);
        __syncthreads();
    }

    // ---- epilogue: D row = lq*4+reg (oc), col = lr (w) ----
    float* ob = out + ((size_t)b * OCH) * WLEN + wt * 64;
#pragma unroll
    for (int mt = 0; mt < 2; ++mt) {
#pragma unroll
        for (int r = 0; r < 4; ++r) {
            int row = wv * 32 + mt * 16 + lq * 4 + r;
            float bv = bias[row];
            float* orow = ob + (size_t)row * WLEN + lr;
#pragma unroll
            for (int nt = 0; nt < 4; ++nt)
                orow[nt * 16] = acc[mt][nt][r] + bv;
        }
    }
}

extern "C" void kernel_launch(void* const* d_in, const int* in_sizes, int n_in,
                              void* d_out, int out_size, void* d_ws, size_t ws_size,
                              hipStream_t stream) {
    const float* x    = (const float*)d_in[0];
    const float* w    = (const float*)d_in[1];
    const float* off  = (const float*)d_in[2];
    const float* msk  = (const float*)d_in[3];
    const float* bias = (const float*)d_in[4];
    float* out = (float*)d_out;
    short* wb  = (short*)d_ws;   // 384 KB bf16 weights

    wconv_kernel<<<768, 256, 0, stream>>>(w, wb);
    deform_fused_kernel<<<BATCH * 64, 512, 0, stream>>>(x, wb, off, msk, bias, out);
}

// Round 4
// 205.106 us; speedup vs baseline: 1.5459x; 1.5459x over previous
//
#include <hip/hip_runtime.h>

#define BATCH 16
#define CCH   256
#define WLEN  4096
#define OCH   256
#define KW    3
#define CK    768      // CCH*KW
#define CHUNK 32       // channels per K-chunk
#define NCHUNK 8       // CCH / CHUNK
#define SLD   104      // Sl row stride (shorts): 96 ck + 8 pad, keeps 16B align

typedef short bf16x8 __attribute__((ext_vector_type(8)));
typedef short bf16x4 __attribute__((ext_vector_type(4)));
typedef float f32x4  __attribute__((ext_vector_type(4)));

__device__ inline short f2bf(float f) {
    union { float f; unsigned u; } v; v.f = f;
    unsigned r = v.u + 0x7FFFu + ((v.u >> 16) & 1u);   // RNE
    return (short)(r >> 16);
}

// ---------------- kernel 1: weight fp32 [256][768] -> bf16 ----------------
__global__ void wconv_kernel(const float* __restrict__ w, short* __restrict__ wb) {
    int i = blockIdx.x * 256 + threadIdx.x;
    wb[i] = f2bf(w[i]);
}

// ---------------- fused kernel v5: direct global taps, NO spill ----------------
// v4 with __launch_bounds__(512,4): the (512,6) variant forced a ~85-reg budget and
// spilled the hot loop to scratch (WRITE_SIZE 65->287 MB, VGPR 52->40). 128 regs/wave
// compiles clean. 2 blocks/CU (reg-bound), LDS 26.6 KB = Sl double-buffer only.
// Gather reads x taps straight from global (12 KB/chunk working set -> L1/L2-hot,
// lanes ~consecutive -> coalesced); x never transits LDS. One barrier per chunk.
__global__ __launch_bounds__(512, 4)
void deform_fused_kernel(const float* __restrict__ x,
                         const short* __restrict__ wb,
                         const float* __restrict__ off,
                         const float* __restrict__ msk,
                         const float* __restrict__ bias,
                         float* __restrict__ out) {
    __shared__ short SlS[2][64 * SLD];       // 2 x 13312 B: gathered B-tile [w][96ck]

    const int t      = threadIdx.x;
    const int b      = blockIdx.x >> 6;
    const int wt     = blockIdx.x & 63;
    const int lane   = t & 63;
    const int wv     = t >> 6;
    const int lr     = lane & 15;
    const int lq     = lane >> 4;
    const int wg     = wt * 64 + lane;

    // ---- per-lane sampling params: clamped global byte offsets + masked weights ----
    int   gb0[3], gb1[3];
    float rw0[3], rw1[3];
#pragma unroll
    for (int k = 0; k < 3; ++k) {
        float o  = off[b * (KW * WLEN) + k * WLEN + wg];
        float m  = msk[b * (KW * WLEN) + k * WLEN + wg];
        float p  = (float)(wg - 1 + k) + o;
        float pf = floorf(p);
        float w1 = p - pf;
        int i0 = (int)pf;
        int i1 = i0 + 1;
        bool v0 = (i0 >= 0) & (i0 < WLEN);
        bool v1 = (i1 >= 0) & (i1 < WLEN);
        gb0[k] = min(max(i0, 0), WLEN - 1) * 4;   // in-bounds byte offset; weight 0 if invalid
        gb1[k] = min(max(i1, 0), WLEN - 1) * 4;
        rw0[k] = v0 ? m * (1.0f - w1) : 0.0f;
        rw1[k] = v1 ? m * w1 : 0.0f;
    }

    const float* xb = x + (size_t)b * CCH * WLEN;

    f32x4 acc[2][4];
#pragma unroll
    for (int i = 0; i < 2; ++i)
#pragma unroll
        for (int j = 0; j < 4; ++j)
            acc[i][j] = (f32x4){0.f, 0.f, 0.f, 0.f};

    // ---- gather chunk c: wave wv samples its 4 channels from GLOBAL -> SlS[sbuf] ----
    auto gather = [&](int c, int sbuf) {
        short obuf[12];
#pragma unroll
        for (int dc = 0; dc < 4; ++dc) {
            const char* xrow = (const char*)(xb + (size_t)(c * CHUNK + wv * 4 + dc) * WLEN);
#pragma unroll
            for (int k = 0; k < 3; ++k) {
                float v0 = *(const float*)(xrow + gb0[k]);
                float v1 = *(const float*)(xrow + gb1[k]);
                obuf[dc * 3 + k] = f2bf(rw0[k] * v0 + rw1[k] * v1);
            }
        }
        short* sp = &SlS[sbuf][lane * SLD + wv * 12];   // cols [wv*12, wv*12+12)
#pragma unroll
        for (int j = 0; j < 3; ++j)
            *reinterpret_cast<bf16x4*>(sp + j * 4) =
                *reinterpret_cast<const bf16x4*>(&obuf[j * 4]);
    };

    // ---- MFMA chunk c: A-frags from global (L2-hot wb), B-frags from SlS[sbuf] ----
    auto mfma_chunk = [&](int c, int sbuf) {
#pragma unroll
        for (int ks = 0; ks < 3; ++ks) {
            bf16x8 af[2], bfv[4];
#pragma unroll
            for (int mt = 0; mt < 2; ++mt)
                af[mt] = *reinterpret_cast<const bf16x8*>(
                    wb + (size_t)(wv * 32 + mt * 16 + lr) * CK + c * 96 + ks * 32 + lq * 8);
#pragma unroll
            for (int nt = 0; nt < 4; ++nt)
                bfv[nt] = *reinterpret_cast<const bf16x8*>(
                    &SlS[sbuf][(nt * 16 + lr) * SLD + ks * 32 + lq * 8]);
            __builtin_amdgcn_s_setprio(1);
#pragma unroll
            for (int mt = 0; mt < 2; ++mt)
#pragma unroll
                for (int nt = 0; nt < 4; ++nt)
                    acc[mt][nt] = __builtin_amdgcn_mfma_f32_16x16x32_bf16(
                        af[mt], bfv[nt], acc[mt][nt], 0, 0, 0);
            __builtin_amdgcn_s_setprio(0);
        }
    };

    // ---- pipeline: gather(c+1) overlaps mfma(c); one barrier per chunk ----
    gather(0, 0);
    __syncthreads();
#pragma unroll
    for (int c = 0; c < NCHUNK; ++c) {
        if (c < NCHUNK - 1) gather(c + 1, (c + 1) & 1);
        mfma_chunk(c, c & 1);
        __syncthreads();
    }

    // ---- epilogue: D row = lq*4+reg (oc), col = lr (w) ----
    float* ob = out + ((size_t)b * OCH) * WLEN + wt * 64;
#pragma unroll
    for (int mt = 0; mt < 2; ++mt) {
#pragma unroll
        for (int r = 0; r < 4; ++r) {
            int row = wv * 32 + mt * 16 + lq * 4 + r;
            float bv = bias[row];
            float* orow = ob + (size_t)row * WLEN + lr;
#pragma unroll
            for (int nt = 0; nt < 4; ++nt)
                orow[nt * 16] = acc[mt][nt][r] + bv;
        }
    }
}

extern "C" void kernel_launch(void* const* d_in, const int* in_sizes, int n_in,
                              void* d_out, int out_size, void* d_ws, size_t ws_size,
                              hipStream_t stream) {
    const float* x    = (const float*)d_in[0];
    const float* w    = (const float*)d_in[1];
    const float* off  = (const float*)d_in[2];
    const float* msk  = (const float*)d_in[3];
    const float* bias = (const float*)d_in[4];
    float* out = (float*)d_out;
    short* wb  = (short*)d_ws;   // 384 KB bf16 weights

    wconv_kernel<<<768, 256, 0, stream>>>(w, wb);
    deform_fused_kernel<<<BATCH * 64, 512, 0, stream>>>(x, wb, off, msk, bias, out);
}